// Round 1
// baseline (409.359 us; speedup 1.0000x reference)
//
#include <hip/hip_runtime.h>

// TemplatePointwiseAttention on MI355X (gfx950)
// B=1, T=4, I=J=256 (P=65536 pixels), C_in=128, heads=4, att_c=64.
//
// Algebraic fusion:
//   scores[t,p,h] = z[p] . M_h . a_t[p],   M_h = sum_{n%4==h} Wq[n](x)Wk[n] / sqrt(128)
//   out[p,m]      = sum_h Abar_h[p] . P_h[m] + bo[m],
//                   Abar_h[p] = sum_t softmax_w[t,p,h] * a_t[p]   (input space!)
//                   P_h[m]    = sum_{n%4==h} Wo[m,n] * Wv[n]
// -> two precomputed 512x128 / 128x512 bf16 matrices (Mcat/Pcat in d_ws),
//    single fused pass over z2d/t2d, two MFMA GEMMs per tile.

#define PIX 65536
#define MT 32            // pixels per workgroup tile

typedef __attribute__((ext_vector_type(8))) short s8v;      // bf16 x8 MFMA frag
typedef __attribute__((ext_vector_type(4))) float f4v;      // fp32 x4 acc
typedef __attribute__((ext_vector_type(4))) unsigned int u4v;
typedef __attribute__((ext_vector_type(4))) unsigned short us4v;
typedef __attribute__((ext_vector_type(4))) float fl4;

__device__ __forceinline__ unsigned short f2bf(float x) {
    unsigned int u = __float_as_uint(x);
    u = (u + 0x7FFFu + ((u >> 16) & 1u)) >> 16;   // round-to-nearest-even
    return (unsigned short)u;
}
__device__ __forceinline__ float bf2fs(short v) {
    return __uint_as_float(((unsigned int)(unsigned short)v) << 16);
}

// Mcat[n=h*128+k2][k1] = (1/sqrt(128)) * sum_c Wq[c*4+h][k1] * Wk[c*4+h][k2]
__global__ __launch_bounds__(256) void build_mcat(const float* __restrict__ Wq,
                                                  const float* __restrict__ Wk,
                                                  unsigned short* __restrict__ mcat) {
    int idx = blockIdx.x * 256 + threadIdx.x;   // 65536 elements
    int n = idx >> 7, k1 = idx & 127;
    int h = n >> 7, k2 = n & 127;
    float s = 0.f;
    #pragma unroll 8
    for (int c = 0; c < 64; c++) {
        int r = c * 4 + h;
        s += Wq[r * 128 + k1] * Wk[r * 128 + k2];
    }
    mcat[idx] = f2bf(s * 0.088388347648318447f);   // 1/sqrt(128)
}

// Pcat[m][kk=h*128+k] = sum_c Wo[m][c*4+h] * Wv[c*4+h][k]
__global__ __launch_bounds__(256) void build_pcat(const float* __restrict__ Wo,
                                                  const float* __restrict__ Wv,
                                                  unsigned short* __restrict__ pcat) {
    int idx = blockIdx.x * 256 + threadIdx.x;   // 65536 elements
    int m = idx >> 9, kk = idx & 511;
    int h = kk >> 7, k = kk & 127;
    float s = 0.f;
    #pragma unroll 8
    for (int c = 0; c < 64; c++) {
        int r = c * 4 + h;
        s += Wo[m * 256 + r] * Wv[r * 128 + k];
    }
    pcat[idx] = f2bf(s);
}

// LDS layout (ushort units); rows padded to 136 (or 520) -> 2-way bank alias only.
#define AZ_OFS 0        // 32 x 136           z tile (bf16)
#define AT_OFS 4352     // 4 x 32 x 136       t tiles (bf16); reused as Pcat stage in phase D
#define UB_OFS 21760    // 32 x 520           u, then Abar (bf16)
#define BB_OFS 38400    // 64 x 136           Mcat stage
#define BUF_USH 47104   // 94208 B  (+ Sc 2048 B = 96256 B total LDS)

__global__ __launch_bounds__(256) void fused_attn(
    const float* __restrict__ z2d, const float* __restrict__ t2d,
    const unsigned short* __restrict__ mcat, const unsigned short* __restrict__ pcat,
    const float* __restrict__ bo, float* __restrict__ out) {

    __shared__ unsigned short buf[BUF_USH];
    __shared__ float Sc[4][32][4];   // scores then softmax weights

    const int tid = threadIdx.x;
    const int pbase = blockIdx.x * MT;

    // ---------------- Phase A: stage z & t tiles fp32->bf16 ----------------
    for (int v = tid; v < 1024; v += 256) {            // 32x128 z elements /4
        int p = v >> 5, k4 = (v & 31) << 2;
        const fl4 d = *(const fl4*)(z2d + (size_t)(pbase + p) * 128 + k4);
        us4v w;
        w[0] = f2bf(d[0]); w[1] = f2bf(d[1]); w[2] = f2bf(d[2]); w[3] = f2bf(d[3]);
        *(us4v*)&buf[AZ_OFS + p * 136 + k4] = w;
    }
    for (int v = tid; v < 4096; v += 256) {            // 4x32x128 t elements /4
        int t = v >> 10, rem = v & 1023, p = rem >> 5, k4 = (rem & 31) << 2;
        const fl4 d = *(const fl4*)(t2d + ((size_t)t * PIX + pbase + p) * 128 + k4);
        us4v w;
        w[0] = f2bf(d[0]); w[1] = f2bf(d[1]); w[2] = f2bf(d[2]); w[3] = f2bf(d[3]);
        *(us4v*)&buf[AT_OFS + (t * 32 + p) * 136 + k4] = w;
    }

    const int wv_id = tid >> 6, lane = tid & 63, quad = lane >> 4, l15 = lane & 15;
    const int mt = wv_id & 1;      // M-tile (16 pixels)
    const int nsel = wv_id >> 1;   // N-split selector

    // ---------------- Phase B: u[32][512] = Z @ Mcat^T ----------------
    for (int nblk = 0; nblk < 8; nblk++) {
        {   // stage 64 Mcat rows (L2-resident weights)
            int row = tid >> 2, seg = tid & 3;
            const u4v* src = (const u4v*)(mcat + (size_t)(nblk * 64 + row) * 128 + seg * 32);
            u4v* dst = (u4v*)&buf[BB_OFS + row * 136 + seg * 32];
            dst[0] = src[0]; dst[1] = src[1]; dst[2] = src[2]; dst[3] = src[3];
        }
        __syncthreads();
        f4v acc0 = {0.f, 0.f, 0.f, 0.f}, acc1 = {0.f, 0.f, 0.f, 0.f};
        #pragma unroll
        for (int ks = 0; ks < 4; ks++) {
            const s8v a  = *(const s8v*)&buf[AZ_OFS + (mt * 16 + l15) * 136 + ks * 32 + quad * 8];
            const s8v b0 = *(const s8v*)&buf[BB_OFS + (nsel * 32 + l15) * 136 + ks * 32 + quad * 8];
            const s8v b1 = *(const s8v*)&buf[BB_OFS + (nsel * 32 + 16 + l15) * 136 + ks * 32 + quad * 8];
            acc0 = __builtin_amdgcn_mfma_f32_16x16x32_bf16(a, b0, acc0, 0, 0, 0);
            acc1 = __builtin_amdgcn_mfma_f32_16x16x32_bf16(a, b1, acc1, 0, 0, 0);
        }
        // C/D layout: row = quad*4+reg, col = lane&15  [verified m89/m91]
        const int prow = mt * 16 + quad * 4;
        const int cbase = nblk * 64 + nsel * 32 + l15;
        #pragma unroll
        for (int r = 0; r < 4; r++) {
            buf[UB_OFS + (prow + r) * 520 + cbase]      = f2bf(acc0[r]);
            buf[UB_OFS + (prow + r) * 520 + cbase + 16] = f2bf(acc1[r]);
        }
        __syncthreads();
    }

    // ---------------- Phase C: scores -> softmax -> Abar ----------------
    {   // scores[t][p][h] = u[p][h*128+:] . a_t[p][:]
        const int p = tid >> 3, t = (tid >> 1) & 3, h2 = tid & 1;  // h in {h2, h2+2}
        float s0 = 0.f, s1 = 0.f;
        const int atb = AT_OFS + (t * 32 + p) * 136;
        const int ub = UB_OFS + p * 520;
        #pragma unroll
        for (int k = 0; k < 128; k += 8) {
            const s8v a8 = *(const s8v*)&buf[atb + k];
            const s8v u0 = *(const s8v*)&buf[ub + h2 * 128 + k];
            const s8v u1 = *(const s8v*)&buf[ub + (h2 + 2) * 128 + k];
            #pragma unroll
            for (int j = 0; j < 8; j++) {
                const float av = bf2fs(a8[j]);
                s0 += bf2fs(u0[j]) * av;
                s1 += bf2fs(u1[j]) * av;
            }
        }
        Sc[t][p][h2] = s0;
        Sc[t][p][h2 + 2] = s1;
    }
    __syncthreads();
    if (tid < 128) {   // softmax over t (4 values) per (p,h)
        const int p = tid >> 2, h = tid & 3;
        float x0 = Sc[0][p][h], x1 = Sc[1][p][h], x2 = Sc[2][p][h], x3 = Sc[3][p][h];
        float mx = fmaxf(fmaxf(x0, x1), fmaxf(x2, x3));
        float e0 = __expf(x0 - mx), e1 = __expf(x1 - mx);
        float e2 = __expf(x2 - mx), e3 = __expf(x3 - mx);
        float inv = 1.f / (e0 + e1 + e2 + e3);
        Sc[0][p][h] = e0 * inv; Sc[1][p][h] = e1 * inv;
        Sc[2][p][h] = e2 * inv; Sc[3][p][h] = e3 * inv;
    }
    __syncthreads();
    {   // Abar_h[p][k] = sum_t w[t,p,h] * a_t[p][k]  -> overwrite u buffer
        const int p = tid >> 3, seg = tid & 7;
        const int h = seg >> 1, k0 = (seg & 1) * 64;
        const float w0 = Sc[0][p][h], w1 = Sc[1][p][h];
        const float w2 = Sc[2][p][h], w3 = Sc[3][p][h];
        const int ab = AT_OFS + p * 136;
        const int stride = 32 * 136;
        for (int k = k0; k < k0 + 64; k += 8) {
            const s8v a0 = *(const s8v*)&buf[ab + 0 * stride + k];
            const s8v a1 = *(const s8v*)&buf[ab + 1 * stride + k];
            const s8v a2 = *(const s8v*)&buf[ab + 2 * stride + k];
            const s8v a3 = *(const s8v*)&buf[ab + 3 * stride + k];
            s8v o;
            #pragma unroll
            for (int j = 0; j < 8; j++) {
                float vs = w0 * bf2fs(a0[j]) + w1 * bf2fs(a1[j])
                         + w2 * bf2fs(a2[j]) + w3 * bf2fs(a3[j]);
                o[j] = (short)f2bf(vs);
            }
            *(s8v*)&buf[UB_OFS + p * 520 + h * 128 + k] = o;
        }
    }
    __syncthreads();

    // ---------------- Phase D: out[32][128] = Abar @ Pcat^T + bo ----------------
    f4v accd[4];
    #pragma unroll
    for (int i = 0; i < 4; i++) accd[i] = (f4v){0.f, 0.f, 0.f, 0.f};
    for (int kblk = 0; kblk < 4; kblk++) {
        {   // stage Pcat[:, kblk*128 : +128] into the (dead) At region
            int row = tid >> 1, seg = tid & 1;
            const u4v* src = (const u4v*)(pcat + (size_t)row * 512 + kblk * 128 + seg * 64);
            u4v* dst = (u4v*)&buf[AT_OFS + row * 136 + seg * 64];
            #pragma unroll
            for (int q = 0; q < 8; q++) dst[q] = src[q];
        }
        __syncthreads();
        #pragma unroll
        for (int ks = 0; ks < 4; ks++) {
            const s8v a = *(const s8v*)&buf[UB_OFS + (mt * 16 + l15) * 520
                                            + kblk * 128 + ks * 32 + quad * 8];
            #pragma unroll
            for (int nt = 0; nt < 4; nt++) {
                const s8v b = *(const s8v*)&buf[AT_OFS + (nsel * 64 + nt * 16 + l15) * 136
                                                + ks * 32 + quad * 8];
                accd[nt] = __builtin_amdgcn_mfma_f32_16x16x32_bf16(a, b, accd[nt], 0, 0, 0);
            }
        }
        __syncthreads();
    }

    // epilogue: add bias, store fp32
    const int prow2 = mt * 16 + quad * 4;
    #pragma unroll
    for (int nt = 0; nt < 4; nt++) {
        const int m = nsel * 64 + nt * 16 + l15;
        const float bb = bo[m];
        #pragma unroll
        for (int r = 0; r < 4; r++) {
            out[(size_t)(pbase + prow2 + r) * 128 + m] = accd[nt][r] + bb;
        }
    }
}

extern "C" void kernel_launch(void* const* d_in, const int* in_sizes, int n_in,
                              void* d_out, int out_size, void* d_ws, size_t ws_size,
                              hipStream_t stream) {
    const float* z2d = (const float*)d_in[0];
    const float* t2d = (const float*)d_in[1];
    const float* Wq  = (const float*)d_in[2];
    const float* Wk  = (const float*)d_in[3];
    const float* Wv  = (const float*)d_in[4];
    const float* Wo  = (const float*)d_in[5];
    const float* bo  = (const float*)d_in[6];

    unsigned short* mcat = (unsigned short*)d_ws;          // 512*128 bf16
    unsigned short* pcat = mcat + 512 * 128;               // 128*512 bf16

    build_mcat<<<256, 256, 0, stream>>>(Wq, Wk, mcat);
    build_pcat<<<256, 256, 0, stream>>>(Wo, Wv, pcat);
    fused_attn<<<PIX / MT, 256, 0, stream>>>(z2d, t2d, mcat, pcat, bo, (float*)d_out);
}

// Round 2
// 343.529 us; speedup vs baseline: 1.1916x; 1.1916x over previous
//
#include <hip/hip_runtime.h>

// TemplatePointwiseAttention on MI355X (gfx950) — round 2
// B=1, T=4, I=J=256 (P=65536 pixels), C_in=128, heads=4, att_c=64.
//
// Algebraic fusion (unchanged from round 1):
//   scores[t,p,h] = z[p] . M_h . a_t[p],   M_h = sum_{n%4==h} Wq[n](x)Wk[n] / sqrt(128)
//   out[p,m]      = sum_h Abar_h[p] . P_h[m] + bo[m],
//                   Abar_h[p] = sum_t softmax_w[t,p,h] * a_t[p]   (input space)
//                   P_h[m]    = sum_{n%4==h} Wo[m,n] * Wv[n]
//
// Round-2 structural changes (occupancy + phase-C VALU):
//   - z tile lives in registers (4 A-frags/lane), no z LDS region
//   - Mcat/Pcat B-frags read directly from global (L2-resident 128 KB each),
//     no weight staging in LDS, no per-nblk barriers
//   - scores via diagonal-of-MFMA (U_h . At^T per 16-pixel tile), not scalar VALU
//   - Abar computed in place over the At region
//   LDS 96.25 KB -> 70.4 KB  => 2 WG/CU;  barriers/tile 22 -> 5

#define PIX 65536
#define MT 32            // pixels per workgroup tile

typedef __attribute__((ext_vector_type(8))) short s8v;      // bf16 x8 MFMA frag
typedef __attribute__((ext_vector_type(4))) float f4v;      // fp32 x4 acc
typedef __attribute__((ext_vector_type(4))) unsigned short us4v;
typedef __attribute__((ext_vector_type(4))) float fl4;

__device__ __forceinline__ unsigned short f2bf(float x) {
    unsigned int u = __float_as_uint(x);
    u = (u + 0x7FFFu + ((u >> 16) & 1u)) >> 16;   // round-to-nearest-even
    return (unsigned short)u;
}
__device__ __forceinline__ float bf2fs(short v) {
    return __uint_as_float(((unsigned int)(unsigned short)v) << 16);
}

// One prologue kernel, 512 blocks: first 256 build Mcat, rest build Pcat.
// Mcat[n=h*128+k2][k1] = (1/sqrt(128)) * sum_c Wq[c*4+h][k1] * Wk[c*4+h][k2]
// Pcat[m][kk=h*128+k]  =                sum_c Wo[m][c*4+h]   * Wv[c*4+h][k]
__global__ __launch_bounds__(256) void build_weights(
        const float* __restrict__ Wq, const float* __restrict__ Wk,
        const float* __restrict__ Wv, const float* __restrict__ Wo,
        unsigned short* __restrict__ mcat, unsigned short* __restrict__ pcat) {
    int b = blockIdx.x;
    if (b < 256) {
        int idx = b * 256 + threadIdx.x;            // 65536 elements
        int n = idx >> 7, k1 = idx & 127;
        int h = n >> 7, k2 = n & 127;
        float s = 0.f;
        #pragma unroll 8
        for (int c = 0; c < 64; c++) {
            int r = c * 4 + h;
            s += Wq[r * 128 + k1] * Wk[r * 128 + k2];
        }
        mcat[idx] = f2bf(s * 0.088388347648318447f);   // 1/sqrt(128)
    } else {
        int idx = (b - 256) * 256 + threadIdx.x;    // 65536 elements
        int m = idx >> 9, kk = idx & 511;
        int h = kk >> 7, k = kk & 127;
        float s = 0.f;
        #pragma unroll 8
        for (int c = 0; c < 64; c++) {
            int r = c * 4 + h;
            s += Wo[m * 256 + r] * Wv[r * 128 + k];
        }
        pcat[idx] = f2bf(s);
    }
}

// LDS (ushort units):
//   At:  4 x 32 x 136  (pad +8 -> 2-way alias only); becomes Abar[h][32][136] in place
//   u :  32 x 524      (pad 524 -> conflict-free C-frag scalar writes)
#define AT_OFS 0
#define U_OFS  17408
#define BUF_USH (17408 + 16768)     // 68,352 B; + Sc 2 KB = 70.4 KB -> 2 WG/CU

__global__ __launch_bounds__(256, 2) void fused_attn(
    const float* __restrict__ z2d, const float* __restrict__ t2d,
    const unsigned short* __restrict__ mcat, const unsigned short* __restrict__ pcat,
    const float* __restrict__ bo, float* __restrict__ out) {

    __shared__ unsigned short buf[BUF_USH];
    __shared__ float Sc[4][32][4];   // scores then softmax weights

    const int tid = threadIdx.x;
    const int pbase = blockIdx.x * MT;
    const int wv = tid >> 6, lane = tid & 63, quad = lane >> 4, l15 = lane & 15;
    const int mt = wv & 1;       // which 16-pixel half this wave's MFMAs cover
    const int nsel = wv >> 1;    // which N-half

    // ---- z A-frags straight into registers (fp32 global -> bf16) ----
    s8v za[4];
    {
        const float* zp = z2d + (size_t)(pbase + mt * 16 + l15) * 128 + quad * 8;
        #pragma unroll
        for (int ks = 0; ks < 4; ks++) {
            const fl4 d0 = *(const fl4*)(zp + ks * 32);
            const fl4 d1 = *(const fl4*)(zp + ks * 32 + 4);
            s8v a;
            a[0] = (short)f2bf(d0[0]); a[1] = (short)f2bf(d0[1]);
            a[2] = (short)f2bf(d0[2]); a[3] = (short)f2bf(d0[3]);
            a[4] = (short)f2bf(d1[0]); a[5] = (short)f2bf(d1[1]);
            a[6] = (short)f2bf(d1[2]); a[7] = (short)f2bf(d1[3]);
            za[ks] = a;
        }
    }

    // ---- stage t tiles fp32 -> bf16 LDS ----
    for (int v = tid; v < 4096; v += 256) {            // 4x32x128 elements /4
        int t = v >> 10, rem = v & 1023, p = rem >> 5, k4 = (rem & 31) << 2;
        const fl4 d = *(const fl4*)(t2d + ((size_t)t * PIX + pbase + p) * 128 + k4);
        us4v w;
        w[0] = f2bf(d[0]); w[1] = f2bf(d[1]); w[2] = f2bf(d[2]); w[3] = f2bf(d[3]);
        *(us4v*)&buf[AT_OFS + (t * 32 + p) * 136 + k4] = w;
    }
    __syncthreads();

    // ---- Phase B: u[32][512] = Z @ Mcat^T; B-frags direct from global (L2) ----
    for (int nblk = 0; nblk < 8; nblk++) {
        s8v b0[4], b1[4];
        #pragma unroll
        for (int ks = 0; ks < 4; ks++) {
            b0[ks] = *(const s8v*)(mcat + (size_t)(nblk * 64 + nsel * 32 + l15) * 128
                                        + ks * 32 + quad * 8);
            b1[ks] = *(const s8v*)(mcat + (size_t)(nblk * 64 + nsel * 32 + 16 + l15) * 128
                                        + ks * 32 + quad * 8);
        }
        f4v acc0 = {0.f, 0.f, 0.f, 0.f}, acc1 = {0.f, 0.f, 0.f, 0.f};
        #pragma unroll
        for (int ks = 0; ks < 4; ks++) {
            acc0 = __builtin_amdgcn_mfma_f32_16x16x32_bf16(za[ks], b0[ks], acc0, 0, 0, 0);
            acc1 = __builtin_amdgcn_mfma_f32_16x16x32_bf16(za[ks], b1[ks], acc1, 0, 0, 0);
        }
        // C/D layout: row = quad*4+r, col = l15
        const int prow = mt * 16 + quad * 4;
        const int cb = nblk * 64 + nsel * 32 + l15;
        #pragma unroll
        for (int r = 0; r < 4; r++) {
            buf[U_OFS + (prow + r) * 524 + cb]      = f2bf(acc0[r]);
            buf[U_OFS + (prow + r) * 524 + cb + 16] = f2bf(acc1[r]);
        }
    }
    __syncthreads();

    // ---- Phase C: scores via diagonal of U_h . At^T (wave = template t) ----
    {
        const int t = wv;
        #pragma unroll
        for (int pt = 0; pt < 2; pt++) {
            s8v bt[4];
            #pragma unroll
            for (int ks = 0; ks < 4; ks++)
                bt[ks] = *(const s8v*)&buf[AT_OFS + (t * 32 + pt * 16 + l15) * 136
                                            + ks * 32 + quad * 8];
            #pragma unroll
            for (int h = 0; h < 4; h++) {
                f4v c = {0.f, 0.f, 0.f, 0.f};
                #pragma unroll
                for (int ks = 0; ks < 4; ks++) {
                    const s8v a = *(const s8v*)&buf[U_OFS + (pt * 16 + l15) * 524
                                                     + h * 128 + ks * 32 + quad * 8];
                    c = __builtin_amdgcn_mfma_f32_16x16x32_bf16(a, bt[ks], c, 0, 0, 0);
                }
                // diagonal element row==col: row = quad*4+r, col = l15
                const int rsel = l15 & 3;
                float dv = rsel == 0 ? c[0] : rsel == 1 ? c[1] : rsel == 2 ? c[2] : c[3];
                if ((l15 >> 2) == quad) Sc[t][pt * 16 + l15][h] = dv;
            }
        }
    }
    __syncthreads();

    // ---- softmax over t per (p,h) ----
    if (tid < 128) {
        const int p = tid >> 2, h = tid & 3;
        float x0 = Sc[0][p][h], x1 = Sc[1][p][h], x2 = Sc[2][p][h], x3 = Sc[3][p][h];
        float mx = fmaxf(fmaxf(x0, x1), fmaxf(x2, x3));
        float e0 = __expf(x0 - mx), e1 = __expf(x1 - mx);
        float e2 = __expf(x2 - mx), e3 = __expf(x3 - mx);
        float inv = 1.f / (e0 + e1 + e2 + e3);
        Sc[0][p][h] = e0 * inv; Sc[1][p][h] = e1 * inv;
        Sc[2][p][h] = e2 * inv; Sc[3][p][h] = e3 * inv;
    }
    __syncthreads();

    // ---- Abar in place over At: each thread owns (p, 16-wide k slice), all t,h ----
    {
        const int p = tid >> 3, seg = tid & 7;
        float w[4][4];
        #pragma unroll
        for (int t = 0; t < 4; t++) {
            const fl4 ww = *(const fl4*)&Sc[t][p][0];
            w[t][0] = ww[0]; w[t][1] = ww[1]; w[t][2] = ww[2]; w[t][3] = ww[3];
        }
        #pragma unroll
        for (int half = 0; half < 2; half++) {
            const int k = seg * 16 + half * 8;
            s8v a[4];
            #pragma unroll
            for (int t = 0; t < 4; t++)
                a[t] = *(const s8v*)&buf[AT_OFS + (t * 32 + p) * 136 + k];
            s8v o[4];
            #pragma unroll
            for (int j = 0; j < 8; j++) {
                const float a0 = bf2fs(a[0][j]), a1 = bf2fs(a[1][j]);
                const float a2 = bf2fs(a[2][j]), a3 = bf2fs(a[3][j]);
                #pragma unroll
                for (int h = 0; h < 4; h++) {
                    o[h][j] = (short)f2bf(w[0][h] * a0 + w[1][h] * a1
                                        + w[2][h] * a2 + w[3][h] * a3);
                }
            }
            #pragma unroll
            for (int h = 0; h < 4; h++)
                *(s8v*)&buf[AT_OFS + (h * 32 + p) * 136 + k] = o[h];
        }
    }
    __syncthreads();

    // ---- Phase D: out[32][128] = Abar @ Pcat^T + bo; Pcat frags from global ----
    f4v accd[4];
    #pragma unroll
    for (int i = 0; i < 4; i++) accd[i] = (f4v){0.f, 0.f, 0.f, 0.f};
    #pragma unroll
    for (int h = 0; h < 4; h++) {          // K blocks of 128 == heads
        s8v af[4];
        #pragma unroll
        for (int ks = 0; ks < 4; ks++)
            af[ks] = *(const s8v*)&buf[AT_OFS + (h * 32 + mt * 16 + l15) * 136
                                        + ks * 32 + quad * 8];
        #pragma unroll
        for (int nt = 0; nt < 4; nt++) {
            #pragma unroll
            for (int ks = 0; ks < 4; ks++) {
                const s8v b = *(const s8v*)(pcat + (size_t)(nsel * 64 + nt * 16 + l15) * 512
                                                 + h * 128 + ks * 32 + quad * 8);
                accd[nt] = __builtin_amdgcn_mfma_f32_16x16x32_bf16(af[ks], b, accd[nt], 0, 0, 0);
            }
        }
    }

    // epilogue: bias + fp32 store
    const int prow2 = mt * 16 + quad * 4;
    #pragma unroll
    for (int nt = 0; nt < 4; nt++) {
        const int m = nsel * 64 + nt * 16 + l15;
        const float bb = bo[m];
        #pragma unroll
        for (int r = 0; r < 4; r++) {
            out[(size_t)(pbase + prow2 + r) * 128 + m] = accd[nt][r] + bb;
        }
    }
}

extern "C" void kernel_launch(void* const* d_in, const int* in_sizes, int n_in,
                              void* d_out, int out_size, void* d_ws, size_t ws_size,
                              hipStream_t stream) {
    const float* z2d = (const float*)d_in[0];
    const float* t2d = (const float*)d_in[1];
    const float* Wq  = (const float*)d_in[2];
    const float* Wk  = (const float*)d_in[3];
    const float* Wv  = (const float*)d_in[4];
    const float* Wo  = (const float*)d_in[5];
    const float* bo  = (const float*)d_in[6];

    unsigned short* mcat = (unsigned short*)d_ws;          // 512*128 bf16
    unsigned short* pcat = mcat + 512 * 128;               // 128*512 bf16

    build_weights<<<512, 256, 0, stream>>>(Wq, Wk, Wv, Wo, mcat, pcat);
    fused_attn<<<PIX / MT, 256, 0, stream>>>(z2d, t2d, mcat, pcat, bo, (float*)d_out);
}

// Round 3
// 325.221 us; speedup vs baseline: 1.2587x; 1.0563x over previous
//
#include <hip/hip_runtime.h>

// TemplatePointwiseAttention on MI355X (gfx950) — round 3
// B=1, T=4, I=J=256 (P=65536 pixels), C_in=128, heads=4, att_c=64.
//
// Algebraic fusion (unchanged):
//   scores[t,p,h] = z[p] . M_h . a_t[p],   M_h = sum_{n%4==h} Wq[n](x)Wk[n] / sqrt(128)
//   out[p,m]      = sum_h Abar_h[p] . P_h[m] + bo[m],
//                   Abar_h[p] = sum_t softmax_w[t,p,h] * a_t[p]   (input space)
//                   P_h[m]    = sum_{n%4==h} Wo[m,n] * Wv[n]
//
// Round-3 change: 16-pixel tiles -> LDS 35 KB -> 4 WG/CU (16 waves/CU),
// grid 4096 WGs. Latency-bound kernel (all pipes <10% in round 2) gets 2x
// the thread-level parallelism to overlap barrier/load stalls.
//   wave roles: phase B wave=u-column quarter; phase C wave=template;
//               phase D wave=output-column quarter.

#define PIX 65536
#define MT 16            // pixels per workgroup tile

typedef __attribute__((ext_vector_type(8))) short s8v;      // bf16 x8 MFMA frag
typedef __attribute__((ext_vector_type(4))) float f4v;      // fp32 x4 acc
typedef __attribute__((ext_vector_type(4))) unsigned short us4v;
typedef __attribute__((ext_vector_type(4))) float fl4;

__device__ __forceinline__ unsigned short f2bf(float x) {
    unsigned int u = __float_as_uint(x);
    u = (u + 0x7FFFu + ((u >> 16) & 1u)) >> 16;   // round-to-nearest-even
    return (unsigned short)u;
}
__device__ __forceinline__ float bf2fs(short v) {
    return __uint_as_float(((unsigned int)(unsigned short)v) << 16);
}

// One prologue kernel, 512 blocks: first 256 build Mcat, rest build Pcat.
// Mcat[n=h*128+k2][k1] = (1/sqrt(128)) * sum_c Wq[c*4+h][k1] * Wk[c*4+h][k2]
// Pcat[m][kk=h*128+k]  =                sum_c Wo[m][c*4+h]   * Wv[c*4+h][k]
__global__ __launch_bounds__(256) void build_weights(
        const float* __restrict__ Wq, const float* __restrict__ Wk,
        const float* __restrict__ Wv, const float* __restrict__ Wo,
        unsigned short* __restrict__ mcat, unsigned short* __restrict__ pcat) {
    int b = blockIdx.x;
    if (b < 256) {
        int idx = b * 256 + threadIdx.x;            // 65536 elements
        int n = idx >> 7, k1 = idx & 127;
        int h = n >> 7, k2 = n & 127;
        float s = 0.f;
        #pragma unroll 8
        for (int c = 0; c < 64; c++) {
            int r = c * 4 + h;
            s += Wq[r * 128 + k1] * Wk[r * 128 + k2];
        }
        mcat[idx] = f2bf(s * 0.088388347648318447f);   // 1/sqrt(128)
    } else {
        int idx = (b - 256) * 256 + threadIdx.x;    // 65536 elements
        int m = idx >> 9, kk = idx & 511;
        int h = kk >> 7, k = kk & 127;
        float s = 0.f;
        #pragma unroll 8
        for (int c = 0; c < 64; c++) {
            int r = c * 4 + h;
            s += Wo[m * 256 + r] * Wv[r * 128 + k];
        }
        pcat[idx] = f2bf(s);
    }
}

// LDS (ushort units):
//   At:  4 x 16 x 136  (pad +8 -> ~2-way bank alias, free); becomes Abar[h][16][136]
//   u :  16 x 524      (pad 524 -> conflict-free scalar C-frag writes & frag reads)
#define AT_OFS 0
#define U_OFS  8704
#define BUF_USH (8704 + 8384)      // 34,176 B; + Sc 1 KB -> ~35.2 KB -> 4 WG/CU

__global__ __launch_bounds__(256, 4) void fused_attn(
    const float* __restrict__ z2d, const float* __restrict__ t2d,
    const unsigned short* __restrict__ mcat, const unsigned short* __restrict__ pcat,
    const float* __restrict__ bo, float* __restrict__ out) {

    __shared__ unsigned short buf[BUF_USH];
    __shared__ float Sc[4][16][4];   // scores then softmax weights

    const int tid = threadIdx.x;
    const int pbase = blockIdx.x * MT;
    const int wv = tid >> 6, lane = tid & 63, quad = lane >> 4, l15 = lane & 15;

    // ---- z A-frags straight into registers (all waves need the same 16 px) ----
    s8v za[4];
    {
        const float* zp = z2d + (size_t)(pbase + l15) * 128 + quad * 8;
        #pragma unroll
        for (int ks = 0; ks < 4; ks++) {
            const fl4 d0 = *(const fl4*)(zp + ks * 32);
            const fl4 d1 = *(const fl4*)(zp + ks * 32 + 4);
            s8v a;
            a[0] = (short)f2bf(d0[0]); a[1] = (short)f2bf(d0[1]);
            a[2] = (short)f2bf(d0[2]); a[3] = (short)f2bf(d0[3]);
            a[4] = (short)f2bf(d1[0]); a[5] = (short)f2bf(d1[1]);
            a[6] = (short)f2bf(d1[2]); a[7] = (short)f2bf(d1[3]);
            za[ks] = a;
        }
    }

    // ---- stage t tiles fp32 -> bf16 LDS (4x16x128 elements, /4 per thread) ----
    #pragma unroll
    for (int i = 0; i < 8; i++) {
        int v = i * 256 + tid;
        int t = v >> 9, rem = v & 511, p = rem >> 5, k4 = (rem & 31) << 2;
        const fl4 d = *(const fl4*)(t2d + ((size_t)t * PIX + pbase + p) * 128 + k4);
        us4v w;
        w[0] = f2bf(d[0]); w[1] = f2bf(d[1]); w[2] = f2bf(d[2]); w[3] = f2bf(d[3]);
        *(us4v*)&buf[AT_OFS + (t * 16 + p) * 136 + k4] = w;
    }
    __syncthreads();

    // ---- Phase B: u[16][512] = Z @ Mcat^T; wave wv owns columns [wv*128, +128) ----
    #pragma unroll
    for (int cb = 0; cb < 8; cb++) {
        const int col = wv * 128 + cb * 16 + l15;    // mcat row index
        s8v b[4];
        #pragma unroll
        for (int ks = 0; ks < 4; ks++)
            b[ks] = *(const s8v*)(mcat + (size_t)col * 128 + ks * 32 + quad * 8);
        f4v acc = {0.f, 0.f, 0.f, 0.f};
        #pragma unroll
        for (int ks = 0; ks < 4; ks++)
            acc = __builtin_amdgcn_mfma_f32_16x16x32_bf16(za[ks], b[ks], acc, 0, 0, 0);
        // C/D layout: row = quad*4+r (pixel), col = l15-part of col
        #pragma unroll
        for (int r = 0; r < 4; r++)
            buf[U_OFS + (quad * 4 + r) * 524 + col] = f2bf(acc[r]);
    }
    __syncthreads();

    // ---- Phase C: scores via diagonal of U_h . At^T (wave = template t) ----
    {
        const int t = wv;
        s8v bt[4];
        #pragma unroll
        for (int ks = 0; ks < 4; ks++)
            bt[ks] = *(const s8v*)&buf[AT_OFS + (t * 16 + l15) * 136 + ks * 32 + quad * 8];
        #pragma unroll
        for (int h = 0; h < 4; h++) {
            f4v c = {0.f, 0.f, 0.f, 0.f};
            #pragma unroll
            for (int ks = 0; ks < 4; ks++) {
                const s8v a = *(const s8v*)&buf[U_OFS + l15 * 524
                                                 + h * 128 + ks * 32 + quad * 8];
                c = __builtin_amdgcn_mfma_f32_16x16x32_bf16(a, bt[ks], c, 0, 0, 0);
            }
            // diagonal row==col: row = quad*4+r, col = l15
            const int rsel = l15 & 3;
            float dv = rsel == 0 ? c[0] : rsel == 1 ? c[1] : rsel == 2 ? c[2] : c[3];
            if ((l15 >> 2) == quad) Sc[t][l15][h] = dv;
        }
    }
    __syncthreads();

    // ---- softmax over t per (p,h) ----
    if (tid < 64) {
        const int p = tid >> 2, h = tid & 3;
        float x0 = Sc[0][p][h], x1 = Sc[1][p][h], x2 = Sc[2][p][h], x3 = Sc[3][p][h];
        float mx = fmaxf(fmaxf(x0, x1), fmaxf(x2, x3));
        float e0 = __expf(x0 - mx), e1 = __expf(x1 - mx);
        float e2 = __expf(x2 - mx), e3 = __expf(x3 - mx);
        float inv = 1.f / (e0 + e1 + e2 + e3);
        Sc[0][p][h] = e0 * inv; Sc[1][p][h] = e1 * inv;
        Sc[2][p][h] = e2 * inv; Sc[3][p][h] = e3 * inv;
    }
    __syncthreads();

    // ---- Abar in place over At: thread owns (p, 8-wide k slice), all t,h ----
    {
        const int p = tid >> 4, seg = tid & 15, k = seg * 8;
        float w[4][4];
        #pragma unroll
        for (int t = 0; t < 4; t++) {
            const fl4 ww = *(const fl4*)&Sc[t][p][0];
            w[t][0] = ww[0]; w[t][1] = ww[1]; w[t][2] = ww[2]; w[t][3] = ww[3];
        }
        s8v a[4];
        #pragma unroll
        for (int t = 0; t < 4; t++)
            a[t] = *(const s8v*)&buf[AT_OFS + (t * 16 + p) * 136 + k];
        s8v o[4];
        #pragma unroll
        for (int j = 0; j < 8; j++) {
            const float a0 = bf2fs(a[0][j]), a1 = bf2fs(a[1][j]);
            const float a2 = bf2fs(a[2][j]), a3 = bf2fs(a[3][j]);
            #pragma unroll
            for (int h = 0; h < 4; h++) {
                o[h][j] = (short)f2bf(w[0][h] * a0 + w[1][h] * a1
                                    + w[2][h] * a2 + w[3][h] * a3);
            }
        }
        #pragma unroll
        for (int h = 0; h < 4; h++)
            *(s8v*)&buf[AT_OFS + (h * 16 + p) * 136 + k] = o[h];
    }
    __syncthreads();

    // ---- Phase D: out[16][128] = Abar @ Pcat^T + bo; wave wv owns cols [wv*32,+32) ----
    f4v accd[2];
    accd[0] = (f4v){0.f, 0.f, 0.f, 0.f};
    accd[1] = (f4v){0.f, 0.f, 0.f, 0.f};
    #pragma unroll
    for (int h = 0; h < 4; h++) {          // K blocks of 128 == heads
        s8v af[4];
        #pragma unroll
        for (int ks = 0; ks < 4; ks++)
            af[ks] = *(const s8v*)&buf[AT_OFS + (h * 16 + l15) * 136 + ks * 32 + quad * 8];
        #pragma unroll
        for (int nt = 0; nt < 2; nt++) {
            #pragma unroll
            for (int ks = 0; ks < 4; ks++) {
                const s8v b = *(const s8v*)(pcat + (size_t)(wv * 32 + nt * 16 + l15) * 512
                                                 + h * 128 + ks * 32 + quad * 8);
                accd[nt] = __builtin_amdgcn_mfma_f32_16x16x32_bf16(af[ks], b, accd[nt], 0, 0, 0);
            }
        }
    }

    // epilogue: bias + fp32 store
    #pragma unroll
    for (int nt = 0; nt < 2; nt++) {
        const int m = wv * 32 + nt * 16 + l15;
        const float bb = bo[m];
        #pragma unroll
        for (int r = 0; r < 4; r++) {
            out[(size_t)(pbase + quad * 4 + r) * 128 + m] = accd[nt][r] + bb;
        }
    }
}

extern "C" void kernel_launch(void* const* d_in, const int* in_sizes, int n_in,
                              void* d_out, int out_size, void* d_ws, size_t ws_size,
                              hipStream_t stream) {
    const float* z2d = (const float*)d_in[0];
    const float* t2d = (const float*)d_in[1];
    const float* Wq  = (const float*)d_in[2];
    const float* Wk  = (const float*)d_in[3];
    const float* Wv  = (const float*)d_in[4];
    const float* Wo  = (const float*)d_in[5];
    const float* bo  = (const float*)d_in[6];

    unsigned short* mcat = (unsigned short*)d_ws;          // 512*128 bf16
    unsigned short* pcat = mcat + 512 * 128;               // 128*512 bf16

    build_weights<<<512, 256, 0, stream>>>(Wq, Wk, Wv, Wo, mcat, pcat);
    fused_attn<<<PIX / MT, 256, 0, stream>>>(z2d, t2d, mcat, pcat, bo, (float*)d_out);
}

// Round 5
// 277.259 us; speedup vs baseline: 1.4764x; 1.1730x over previous
//
#include <hip/hip_runtime.h>

// TemplatePointwiseAttention on MI355X (gfx950) — round 5
// B=1, T=4, I=J=256 (P=65536 pixels), C_in=128, heads=4, att_c=64.
//
// Algebraic fusion (unchanged):
//   scores[t,p,h] = z[p] . M_h . a_t[p],   M_h = sum_{n%4==h} Wq[n](x)Wk[n] / sqrt(128)
//   out[p,m]      = sum_h Abar_h[p] . P_h[m] + bo[m],
//                   Abar_h[p] = sum_t softmax_w[t,p,h] * a_t[p]   (input space)
//                   P_h[m]    = sum_{n%4==h} Wo[m,n] * Wv[n]
//
// Round-5 = round-4 structure with two fixes:
//   FIX 1: mcat LDS staging index (128-ush row = 16 x 16B units, not 8):
//          row = g8>>4, c8 = g8&15  (round 4 wrote LDS out of bounds -> NaN)
//   FIX 2: __threadfence_block() around the intra-wave scr round-trip
//          (cross-lane LDS communication needs compiler-visible ordering)

#define PIX 65536

typedef __attribute__((ext_vector_type(8))) short s8v;      // bf16 x8 MFMA frag
typedef __attribute__((ext_vector_type(4))) float f4v;      // fp32 x4 acc
typedef __attribute__((ext_vector_type(4))) unsigned int u4v;
typedef __attribute__((ext_vector_type(4))) float fl4;

__device__ __forceinline__ unsigned short f2bf(float x) {
    unsigned int u = __float_as_uint(x);
    u = (u + 0x7FFFu + ((u >> 16) & 1u)) >> 16;   // round-to-nearest-even
    return (unsigned short)u;
}
__device__ __forceinline__ float bf2fs(short v) {
    return __uint_as_float(((unsigned int)(unsigned short)v) << 16);
}

// Prologue: Mcat[n=h*128+k2][k1] = (1/sqrt128) sum_c Wq[c*4+h][k1] Wk[c*4+h][k2]
//           Pcat[m][kk=h*128+k]  = sum_c Wo[m][c*4+h] Wv[c*4+h][k]
__global__ __launch_bounds__(256) void build_weights(
        const float* __restrict__ Wq, const float* __restrict__ Wk,
        const float* __restrict__ Wv, const float* __restrict__ Wo,
        unsigned short* __restrict__ mcat, unsigned short* __restrict__ pcat) {
    int b = blockIdx.x;
    if (b < 256) {
        int idx = b * 256 + threadIdx.x;
        int n = idx >> 7, k1 = idx & 127;
        int h = n >> 7, k2 = n & 127;
        float s = 0.f;
        #pragma unroll 8
        for (int c = 0; c < 64; c++) {
            int r = c * 4 + h;
            s += Wq[r * 128 + k1] * Wk[r * 128 + k2];
        }
        mcat[idx] = f2bf(s * 0.088388347648318447f);
    } else {
        int idx = (b - 256) * 256 + threadIdx.x;
        int m = idx >> 9, kk = idx & 511;
        int h = kk >> 7, k = kk & 127;
        float s = 0.f;
        #pragma unroll 8
        for (int c = 0; c < 64; c++) {
            int r = c * 4 + h;
            s += Wo[m * 256 + r] * Wv[r * 128 + k];
        }
        pcat[idx] = f2bf(s);
    }
}

// ======================= Kernel S: scores + softmax =======================
// LDS: mcat [512][136] (stride 68 words = 4 mod 32 -> <=2-way banks; rows 16B-aligned)
//      + per-wave u scratch [16][72]
#define S_SCR_OFS (512 * 136)                    // 69632 ush
#define S_USH (S_SCR_OFS + 8 * 16 * 72)          // 78848 ush = 157,696 B

__global__ __launch_bounds__(512, 2) void score_kernel(
    const float* __restrict__ z2d, const float* __restrict__ t2d,
    const unsigned short* __restrict__ mcat, float* __restrict__ wbuf) {

    __shared__ unsigned short sm[S_USH];
    const int tid = threadIdx.x;

    // stage mcat (coalesced 16B units) — once per WG.  FIX 1: 16 units/row.
    #pragma unroll
    for (int i = 0; i < 16; i++) {
        int g8 = i * 512 + tid;                  // 16B-unit index, 8192 total
        int row = g8 >> 4, c8 = g8 & 15;
        *(u4v*)&sm[row * 136 + c8 * 8] = *(const u4v*)(mcat + (size_t)g8 * 8);
    }
    __syncthreads();   // the only barrier

    const int wv = tid >> 6, lane = tid & 63, quad = lane >> 4, l15 = lane & 15;
    unsigned short* scr = &sm[S_SCR_OFS + wv * (16 * 72)];

    for (int it = 0; it < 2; it++) {
        const int p0 = blockIdx.x * 256 + (wv * 2 + it) * 16;

        // z A-frags (fp32 global -> bf16 regs)
        s8v za[4];
        {
            const float* zp = z2d + (size_t)(p0 + l15) * 128 + quad * 8;
            #pragma unroll
            for (int ks = 0; ks < 4; ks++) {
                const fl4 d0 = *(const fl4*)(zp + ks * 32);
                const fl4 d1 = *(const fl4*)(zp + ks * 32 + 4);
                s8v a;
                a[0] = (short)f2bf(d0[0]); a[1] = (short)f2bf(d0[1]);
                a[2] = (short)f2bf(d0[2]); a[3] = (short)f2bf(d0[3]);
                a[4] = (short)f2bf(d1[0]); a[5] = (short)f2bf(d1[1]);
                a[6] = (short)f2bf(d1[2]); a[7] = (short)f2bf(d1[3]);
                za[ks] = a;
            }
        }
        // a_t B-frags for the diagonal-score MFMA (4t x 4kf)
        s8v atf[4][4];
        #pragma unroll
        for (int t = 0; t < 4; t++) {
            const float* ap = t2d + ((size_t)t * PIX + p0 + l15) * 128 + quad * 8;
            #pragma unroll
            for (int kf = 0; kf < 4; kf++) {
                const fl4 d0 = *(const fl4*)(ap + kf * 32);
                const fl4 d1 = *(const fl4*)(ap + kf * 32 + 4);
                s8v a;
                a[0] = (short)f2bf(d0[0]); a[1] = (short)f2bf(d0[1]);
                a[2] = (short)f2bf(d0[2]); a[3] = (short)f2bf(d0[3]);
                a[4] = (short)f2bf(d1[0]); a[5] = (short)f2bf(d1[1]);
                a[6] = (short)f2bf(d1[2]); a[7] = (short)f2bf(d1[3]);
                atf[t][kf] = a;
            }
        }

        for (int h = 0; h < 4; h++) {
            f4v dac[4];
            #pragma unroll
            for (int t = 0; t < 4; t++) dac[t] = (f4v){0.f, 0.f, 0.f, 0.f};

            #pragma unroll
            for (int ph = 0; ph < 2; ph++) {      // halves of u's 128 cols
                f4v uacc[4];
                #pragma unroll
                for (int c = 0; c < 4; c++) {
                    const int brow = h * 128 + (ph * 4 + c) * 16 + l15;
                    f4v acc = {0.f, 0.f, 0.f, 0.f};
                    #pragma unroll
                    for (int ks = 0; ks < 4; ks++) {
                        const s8v b = *(const s8v*)&sm[brow * 136 + ks * 32 + quad * 8];
                        acc = __builtin_amdgcn_mfma_f32_16x16x32_bf16(za[ks], b, acc, 0, 0, 0);
                    }
                    uacc[c] = acc;
                }
                // C-layout (row=quad*4+r pixel, col=l15) -> per-wave scratch
                #pragma unroll
                for (int c = 0; c < 4; c++)
                    #pragma unroll
                    for (int r = 0; r < 4; r++)
                        scr[(quad * 4 + r) * 72 + c * 16 + l15] = f2bf(uacc[c][r]);
                __threadfence_block();   // FIX 2: order cross-lane LDS WAR/RAW
                // A-frags from scratch, accumulate diagonal scores over k
                #pragma unroll
                for (int ks2 = 0; ks2 < 2; ks2++) {
                    const s8v uf = *(const s8v*)&scr[l15 * 72 + ks2 * 32 + quad * 8];
                    const int kf = ph * 2 + ks2;
                    #pragma unroll
                    for (int t = 0; t < 4; t++)
                        dac[t] = __builtin_amdgcn_mfma_f32_16x16x32_bf16(
                            uf, atf[t][kf], dac[t], 0, 0, 0);
                }
                __threadfence_block();   // FIX 2: before next ph overwrites scr
            }
            // diagonal holder lanes: row(quad*4+r) == col(l15)
            if ((l15 >> 2) == quad) {
                const int r = l15 & 3;
                float x0 = r == 0 ? dac[0][0] : r == 1 ? dac[0][1] : r == 2 ? dac[0][2] : dac[0][3];
                float x1 = r == 0 ? dac[1][0] : r == 1 ? dac[1][1] : r == 2 ? dac[1][2] : dac[1][3];
                float x2 = r == 0 ? dac[2][0] : r == 1 ? dac[2][1] : r == 2 ? dac[2][2] : dac[2][3];
                float x3 = r == 0 ? dac[3][0] : r == 1 ? dac[3][1] : r == 2 ? dac[3][2] : dac[3][3];
                float mx = fmaxf(fmaxf(x0, x1), fmaxf(x2, x3));
                float e0 = __expf(x0 - mx), e1 = __expf(x1 - mx);
                float e2 = __expf(x2 - mx), e3 = __expf(x3 - mx);
                float inv = 1.f / (e0 + e1 + e2 + e3);
                float* wp = wbuf + (size_t)h * 4 * PIX + p0 + l15;
                wp[0 * PIX] = e0 * inv; wp[1 * PIX] = e1 * inv;
                wp[2 * PIX] = e2 * inv; wp[3 * PIX] = e3 * inv;
            }
        }
    }
}

// ======================= Kernel O: Abar + output GEMM =======================
// LDS: pcat [128][520] (stride 260 words = 4 mod 32 -> <=2-way banks)
#define O_USH (128 * 520)                        // 66560 ush = 133,120 B

__global__ __launch_bounds__(512, 2) void out_kernel(
    const float* __restrict__ t2d, const unsigned short* __restrict__ pcat,
    const float* __restrict__ wbuf, const float* __restrict__ bo,
    float* __restrict__ out) {

    __shared__ unsigned short sm[O_USH];
    const int tid = threadIdx.x;

    // stage pcat — once per WG (512-ush row = 64 x 16B units)
    #pragma unroll
    for (int i = 0; i < 16; i++) {
        int g8 = i * 512 + tid;                  // 8192 x 16B
        int row = g8 >> 6, c8 = g8 & 63;
        *(u4v*)&sm[row * 520 + c8 * 8] = *(const u4v*)(pcat + (size_t)g8 * 8);
    }
    __syncthreads();   // the only barrier

    const int wv = tid >> 6, lane = tid & 63, quad = lane >> 4, l15 = lane & 15;
    const int p0 = blockIdx.x * 256 + wv * 32;   // 32 px per wave

    // softmax weights for this wave's 32 pixels
    float wgt[4][2][4];                          // [t][mt][h]
    #pragma unroll
    for (int h = 0; h < 4; h++)
        #pragma unroll
        for (int t = 0; t < 4; t++)
            #pragma unroll
            for (int mt = 0; mt < 2; mt++)
                wgt[t][mt][h] = wbuf[(size_t)(h * 4 + t) * PIX + p0 + mt * 16 + l15];

    f4v acc[2][8];
    #pragma unroll
    for (int mt = 0; mt < 2; mt++)
        #pragma unroll
        for (int ct = 0; ct < 8; ct++) acc[mt][ct] = (f4v){0.f, 0.f, 0.f, 0.f};

    #pragma unroll
    for (int ks = 0; ks < 4; ks++) {             // K-within-head, outer
        // t2d slices for this ks (4t x 2mt), fp32 -> bf16 regs
        s8v ab[4][2];
        #pragma unroll
        for (int t = 0; t < 4; t++)
            #pragma unroll
            for (int mt = 0; mt < 2; mt++) {
                const float* ap = t2d + ((size_t)t * PIX + p0 + mt * 16 + l15) * 128
                                  + ks * 32 + quad * 8;
                const fl4 d0 = *(const fl4*)ap;
                const fl4 d1 = *(const fl4*)(ap + 4);
                s8v a;
                a[0] = (short)f2bf(d0[0]); a[1] = (short)f2bf(d0[1]);
                a[2] = (short)f2bf(d0[2]); a[3] = (short)f2bf(d0[3]);
                a[4] = (short)f2bf(d1[0]); a[5] = (short)f2bf(d1[1]);
                a[6] = (short)f2bf(d1[2]); a[7] = (short)f2bf(d1[3]);
                ab[t][mt] = a;
            }
        #pragma unroll
        for (int h = 0; h < 4; h++) {
            // Abar A-frags in registers
            s8v af[2];
            #pragma unroll
            for (int mt = 0; mt < 2; mt++) {
                s8v o;
                #pragma unroll
                for (int j = 0; j < 8; j++) {
                    float v = wgt[0][mt][h] * bf2fs(ab[0][mt][j])
                            + wgt[1][mt][h] * bf2fs(ab[1][mt][j])
                            + wgt[2][mt][h] * bf2fs(ab[2][mt][j])
                            + wgt[3][mt][h] * bf2fs(ab[3][mt][j]);
                    o[j] = (short)f2bf(v);
                }
                af[mt] = o;
            }
            #pragma unroll
            for (int ct = 0; ct < 8; ct++) {
                const s8v b = *(const s8v*)&sm[(ct * 16 + l15) * 520
                                               + h * 128 + ks * 32 + quad * 8];
                acc[0][ct] = __builtin_amdgcn_mfma_f32_16x16x32_bf16(af[0], b, acc[0][ct], 0, 0, 0);
                acc[1][ct] = __builtin_amdgcn_mfma_f32_16x16x32_bf16(af[1], b, acc[1][ct], 0, 0, 0);
            }
        }
    }

    // epilogue: bias + fp32 store
    #pragma unroll
    for (int ct = 0; ct < 8; ct++) {
        const float bb = bo[ct * 16 + l15];
        #pragma unroll
        for (int mt = 0; mt < 2; mt++)
            #pragma unroll
            for (int r = 0; r < 4; r++)
                out[(size_t)(p0 + mt * 16 + quad * 4 + r) * 128 + ct * 16 + l15]
                    = acc[mt][ct][r] + bb;
    }
}

extern "C" void kernel_launch(void* const* d_in, const int* in_sizes, int n_in,
                              void* d_out, int out_size, void* d_ws, size_t ws_size,
                              hipStream_t stream) {
    const float* z2d = (const float*)d_in[0];
    const float* t2d = (const float*)d_in[1];
    const float* Wq  = (const float*)d_in[2];
    const float* Wk  = (const float*)d_in[3];
    const float* Wv  = (const float*)d_in[4];
    const float* Wo  = (const float*)d_in[5];
    const float* bo  = (const float*)d_in[6];

    unsigned short* mcat = (unsigned short*)d_ws;          // 512*128 bf16 = 128 KB
    unsigned short* pcat = mcat + 512 * 128;               // 128*512 bf16 = 128 KB
    float* wbuf = (float*)(pcat + 128 * 512);              // 16*65536 fp32 = 4 MB

    build_weights<<<512, 256, 0, stream>>>(Wq, Wk, Wv, Wo, mcat, pcat);
    score_kernel<<<256, 512, 0, stream>>>(z2d, t2d, mcat, wbuf);
    out_kernel<<<256, 512, 0, stream>>>(t2d, pcat, wbuf, bo, (float*)d_out);
}